// Round 3
// baseline (127.644 us; speedup 1.0000x reference)
//
#include <hip/hip_runtime.h>
#include <stdint.h>

// CandidateFinder: binary-quantize (x>0), exact match on two 32-bit dim
// groups (union), gather first <=64 matching key indices per query, pad -1.
//
// R2 -> R3: R1/R2 showed dur_us pinned at ~70us regardless of match-kernel
// structure -> the timed window is dominated by harness reset fills (268MB
// d_ws poison = 40us) + per-launch overhead. Only reducible term: number of
// launches. This round: ONE fused kernel, no d_ws.
//
// Signature packing: lane covers 4 dims (float4), packs a nibble; 8 nibbles
// OR-combined into each 32-bit group word via 3 shfl_xor. This is a fixed
// within-group bit permutation of the canonical signature — equality per
// 32-bit group is invariant under it, and Q and K use identical packing, so
// match semantics are exact. Matches emitted in ascending key order via
// ballot+popcount prefix = reference's sort-then-truncate.

#define LSEQ 2048
#define DDIM 64
#define KMAX 64
#define QPB  32   // queries per block -> B*64 = 256 blocks = 1/CU

// Pack lane's float4 sign nibble and OR-combine across each 16-lane row
// segment into the two 32-bit group words. Returns the row signature in
// lanes with (lane&15)==0 (x = dims 0..31 group, y = dims 32..63 group).
__device__ __forceinline__ uint2 pack4rows(float4 v, int sub) {
    unsigned n = (v.x > 0.f ? 1u : 0u) | (v.y > 0.f ? 2u : 0u)
               | (v.z > 0.f ? 4u : 0u) | (v.w > 0.f ? 8u : 0u);
    unsigned x = n << (4 * (sub & 7));
    x |= __shfl_xor(x, 1);      // OR-reduce over 8-lane half-segments
    x |= __shfl_xor(x, 2);
    x |= __shfl_xor(x, 4);
    unsigned y = __shfl_down(x, 8);   // group-B word into the j==0 lane
    return make_uint2(x, y);
}

__global__ __launch_bounds__(256) void cand_kernel(
    const float* __restrict__ query, const float* __restrict__ key,
    int* __restrict__ out) {
    __shared__ uint2 ks[LSEQ];      // 16 KB: batch's key signatures
    __shared__ uint2 qs[QPB];       // this block's query signatures

    const int bpb  = LSEQ / QPB;    // blocks per batch = 64
    int b    = blockIdx.x / bpb;
    int qblk = blockIdx.x % bpb;
    int lane = threadIdx.x & 63;
    int wave = threadIdx.x >> 6;
    int sub  = lane & 15;           // float4 index within the row
    int rsub = lane >> 4;           // which of the 4 rows this lane covers

    // ---- stage key signatures: 512 rows/wave, 4 rows per iteration ----
    const float4* kb4 = (const float4*)(key + (size_t)b * LSEQ * DDIM);
    for (int i = 0; i < LSEQ / 4 / 4; ++i) {        // 128 iters
        int row = wave * (LSEQ / 4) + i * 4 + rsub;
        float4 v = kb4[row * 16 + sub];             // 1KB/wave coalesced
        uint2 s = pack4rows(v, sub);
        if (sub == 0) ks[row] = s;
    }
    // ---- stage this block's 32 query signatures: 2 iterations/wave ----
    const float4* qb4 =
        (const float4*)(query + ((size_t)b * LSEQ + (size_t)qblk * QPB) * DDIM);
    for (int i = 0; i < QPB / 4 / 4 / 2; ++i) {     // 1 iter (8 rows/wave? no:)
        // unreachable placeholder; real loop below
    }
    for (int i = 0; i < 2; ++i) {                   // 8 rows per wave
        int row = wave * 8 + i * 4 + rsub;          // local 0..31
        float4 v = qb4[row * 16 + sub];
        uint2 s = pack4rows(v, sub);
        if (sub == 0) qs[row] = s;
    }
    __syncthreads();

    // ---- scan: 8 queries per wave, 32 chunks of 64 keys (one/lane) ----
    unsigned long long below = (1ull << lane) - 1ull;
    for (int t = 0; t < QPB / 4; ++t) {
        int ql = wave * (QPB / 4) + t;
        uint2 q = qs[ql];                           // wave-uniform broadcast
        int* obase = out + ((size_t)b * LSEQ + (size_t)qblk * QPB + ql) * KMAX;
        int cnt = 0;
#pragma unroll 8
        for (int c = 0; c < LSEQ / 64; ++c) {
            uint2 kv = ks[c * 64 + lane];           // 2-way bank alias: free
            bool m = (kv.x == q.x) || (kv.y == q.y);
            unsigned long long mask = __ballot(m);
            if (m) {                                // ~never taken (p~2^-31)
                int pos = cnt + __popcll(mask & below);
                if (pos < KMAX) obase[pos] = c * 64 + lane;
            }
            cnt += __popcll(mask);                  // wave-uniform scalar
        }
        // pad remaining slots with -1 (KMAX == 64 lanes; disjoint vs matches)
        if (lane >= cnt) obase[lane] = -1;
    }
}

extern "C" void kernel_launch(void* const* d_in, const int* in_sizes, int n_in,
                              void* d_out, int out_size, void* d_ws, size_t ws_size,
                              hipStream_t stream) {
    const float* q = (const float*)d_in[0];
    const float* k = (const float*)d_in[1];
    // d_in[2] = head_idx, unused (inputs are already per-head)
    int* out = (int*)d_out;

    int total = in_sizes[0];             // B * L * D
    int B = total / (LSEQ * DDIM);       // = 4

    cand_kernel<<<B * (LSEQ / QPB), 256, 0, stream>>>(q, k, out);
}

// Round 4
// 98.466 us; speedup vs baseline: 1.2963x; 1.2963x over previous
//
#include <hip/hip_runtime.h>
#include <stdint.h>

// CandidateFinder: binary-quantize (x>0), exact match on two 32-bit dim
// groups (union), gather first <=64 matching key indices per query, pad -1.
//
// R3 -> R4: R3's fused kernel was 80us: 256x256 launch = 1 wave/SIMD
// (Occupancy 11%) with chained shfl packing (4 serialized DS ops/iter) ->
// latency-starved. Fix: 1024-thread blocks (16 waves/block -> real TLP) and
// one-ballot-per-row packing (lane=dim, one coalesced 256B row load, one
// v_cmp+ballot, 8B LDS write) — no shuffle chains. Still ONE launch (R3
// showed ~47us of harness floor + ~8-10us per extra kernel node).
//
// wave=64 lanes <-> 64 dims: __ballot(v>0) IS the row's two 32-bit group
// signatures in canonical bit order. Matches emitted in ascending key order
// via ballot+popcount prefix = reference's sort-then-truncate.

#define LSEQ 2048
#define DDIM 64
#define KMAX 64
#define QPB  32   // queries per block -> grid = B * 64 = 256 blocks
#define NW   16   // waves per block (1024 threads)

__global__ __launch_bounds__(1024) void cand_kernel(
    const float* __restrict__ query, const float* __restrict__ key,
    int* __restrict__ out) {
    __shared__ uint2 ks[LSEQ];          // 16 KB: this batch's key signatures

    const int bpb  = LSEQ / QPB;        // 64 blocks per batch
    int b    = blockIdx.x / bpb;
    int qblk = blockIdx.x % bpb;
    int lane = threadIdx.x & 63;
    int wave = threadIdx.x >> 6;

    // ---- pack all 2048 key rows: 128 rows/wave, 1 ballot each ----
    const float* kb = key + (size_t)b * LSEQ * DDIM;
#pragma unroll 8
    for (int i = 0; i < LSEQ / NW; ++i) {
        int row = i * NW + wave;
        float v = kb[(size_t)row * DDIM + lane];    // coalesced 256B/wave
        unsigned long long m = __ballot(v > 0.0f);  // bit i = dim i sign
        if (lane == 0)
            ks[row] = make_uint2((unsigned)m, (unsigned)(m >> 32));
    }

    // ---- this wave's 2 query signatures (kept in registers) ----
    const float* qb = query + ((size_t)b * LSEQ + (size_t)qblk * QPB) * DDIM;
    int q0 = wave * 2;                              // local query idx
    float v0 = qb[(size_t)q0 * DDIM + lane];
    float v1 = qb[(size_t)(q0 + 1) * DDIM + lane];
    unsigned long long m0 = __ballot(v0 > 0.0f);
    unsigned long long m1 = __ballot(v1 > 0.0f);

    __syncthreads();

    // ---- scan: 2 queries/wave x 32 chunks of 64 keys (one key/lane) ----
    unsigned long long below = (1ull << lane) - 1ull;
    for (int t = 0; t < 2; ++t) {
        unsigned long long qm = t ? m1 : m0;
        unsigned q1 = (unsigned)qm, q2 = (unsigned)(qm >> 32);
        int* obase =
            out + ((size_t)b * LSEQ + (size_t)qblk * QPB + q0 + t) * KMAX;
        int cnt = 0;
#pragma unroll 8
        for (int c = 0; c < LSEQ / 64; ++c) {
            uint2 kv = ks[c * 64 + lane];           // 2-way bank alias: free
            bool m = (kv.x == q1) || (kv.y == q2);
            unsigned long long mask = __ballot(m);
            if (m) {                                // ~never taken (p~2^-31)
                int pos = cnt + __popcll(mask & below);
                if (pos < KMAX) obase[pos] = c * 64 + lane;
            }
            cnt += __popcll(mask);                  // wave-uniform scalar
        }
        // pad remaining slots with -1 (KMAX == 64 lanes; disjoint vs matches)
        if (lane >= cnt) obase[lane] = -1;
    }
}

extern "C" void kernel_launch(void* const* d_in, const int* in_sizes, int n_in,
                              void* d_out, int out_size, void* d_ws, size_t ws_size,
                              hipStream_t stream) {
    const float* q = (const float*)d_in[0];
    const float* k = (const float*)d_in[1];
    // d_in[2] = head_idx, unused (inputs are already per-head)
    int* out = (int*)d_out;

    int total = in_sizes[0];             // B * L * D
    int B = total / (LSEQ * DDIM);       // = 4

    cand_kernel<<<B * (LSEQ / QPB), 1024, 0, stream>>>(q, k, out);
}

// Round 5
// 72.569 us; speedup vs baseline: 1.7589x; 1.3569x over previous
//
#include <hip/hip_runtime.h>
#include <stdint.h>

// CandidateFinder: binary-quantize (x>0), exact match on two 32-bit dim
// groups (union), gather first <=64 matching key indices per query, pad -1.
//
// R4 -> R5: R4's kernel was 50us = 128 staging iters x ~900cyc HBM
// round-trip: the divergent `if(lane==0)` store inside each unrolled
// iteration split basic blocks, so the scheduler never batched the loads
// (one in flight per wave). Fix: branch-free load groups of 32 (all loads
// in one BB -> 32 in flight), ballots are scalar/branchless, stores merged
// under a single exec-toggle. Scan loop made fully branchless (acc|=mask,
// cnt+=popcll are scalar); exact emit moved to a wave-uniform rare path
// (p ~ 2^-26) that re-runs the original loop. Still ONE launch (~47us of
// the wall is harness reset floor).
//
// wave=64 lanes <-> 64 dims: __ballot(v>0) IS the row's two 32-bit group
// signatures in canonical bit order. Matches emitted in ascending key order
// via ballot+popcount prefix = reference's sort-then-truncate.

#define LSEQ 2048
#define DDIM 64
#define KMAX 64
#define QPB  32   // queries per block -> grid = B * 64 = 256 blocks
#define NW   16   // waves per block (1024 threads)
#define GROUP 32  // rows loaded branch-free per wave per pass

__global__ __launch_bounds__(1024) void cand_kernel(
    const float* __restrict__ query, const float* __restrict__ key,
    int* __restrict__ out) {
    __shared__ uint2 ks[LSEQ];          // 16 KB: this batch's key signatures

    const int bpb  = LSEQ / QPB;        // 64 blocks per batch
    int b    = blockIdx.x / bpb;
    int qblk = blockIdx.x % bpb;
    int lane = threadIdx.x & 63;
    int wave = threadIdx.x >> 6;

    // ---- pack all 2048 key rows: 128 rows/wave in 4 branch-free groups ----
    const float* kb = key + (size_t)b * LSEQ * DDIM;
    for (int g = 0; g < LSEQ / NW / GROUP; ++g) {   // 4 groups
        float v[GROUP];
#pragma unroll
        for (int u = 0; u < GROUP; ++u) {           // 32 loads, one BB,
            int row = g * (NW * GROUP) + u * NW + wave;
            v[u] = kb[(size_t)row * DDIM + lane];   // all in flight
        }
        unsigned long long m[GROUP];
#pragma unroll
        for (int u = 0; u < GROUP; ++u)             // branchless (scalar dst)
            m[u] = __ballot(v[u] > 0.0f);
        if (lane == 0) {                            // ONE exec toggle / group
#pragma unroll
            for (int u = 0; u < GROUP; ++u) {
                int row = g * (NW * GROUP) + u * NW + wave;
                ks[row] = make_uint2((unsigned)m[u], (unsigned)(m[u] >> 32));
            }
        }
    }

    // ---- this wave's 2 query signatures (kept in scalar regs) ----
    const float* qb = query + ((size_t)b * LSEQ + (size_t)qblk * QPB) * DDIM;
    int q0 = wave * 2;                              // local query idx
    float v0 = qb[(size_t)q0 * DDIM + lane];
    float v1 = qb[(size_t)(q0 + 1) * DDIM + lane];
    unsigned long long m0 = __ballot(v0 > 0.0f);
    unsigned long long m1 = __ballot(v1 > 0.0f);

    __syncthreads();

    // ---- scan: 2 queries/wave x 32 chunks of 64 keys (one key/lane) ----
    unsigned long long below = (1ull << lane) - 1ull;
    for (int t = 0; t < 2; ++t) {
        unsigned long long qm = t ? m1 : m0;
        unsigned q1 = (unsigned)qm, q2 = (unsigned)(qm >> 32);
        int* obase =
            out + ((size_t)b * LSEQ + (size_t)qblk * QPB + q0 + t) * KMAX;

        // fast path: fully branchless -> 32 ds_read_b64 back-to-back
        unsigned long long acc = 0;
        int cnt = 0;
#pragma unroll
        for (int c = 0; c < LSEQ / 64; ++c) {
            uint2 kv = ks[c * 64 + lane];           // 2-way bank alias: free
            bool m = (kv.x == q1) || (kv.y == q2);
            unsigned long long mask = __ballot(m);
            acc |= mask;                            // s_or_b64
            cnt += __popcll(mask);                  // s_bcnt1 + s_add
        }

        if (acc != 0) {                             // wave-uniform, p~2^-26:
            int c2 = 0;                             // exact emit, orig loop
            for (int c = 0; c < LSEQ / 64; ++c) {
                uint2 kv = ks[c * 64 + lane];
                bool m = (kv.x == q1) || (kv.y == q2);
                unsigned long long mask = __ballot(m);
                if (m) {
                    int pos = c2 + __popcll(mask & below);
                    if (pos < KMAX) obase[pos] = c * 64 + lane;
                }
                c2 += __popcll(mask);
            }
        }
        // pad remaining slots with -1 (KMAX == 64 lanes; disjoint vs matches)
        if (lane >= cnt) obase[lane] = -1;
    }
}

extern "C" void kernel_launch(void* const* d_in, const int* in_sizes, int n_in,
                              void* d_out, int out_size, void* d_ws, size_t ws_size,
                              hipStream_t stream) {
    const float* q = (const float*)d_in[0];
    const float* k = (const float*)d_in[1];
    // d_in[2] = head_idx, unused (inputs are already per-head)
    int* out = (int*)d_out;

    int total = in_sizes[0];             // B * L * D
    int B = total / (LSEQ * DDIM);       // = 4

    cand_kernel<<<B * (LSEQ / QPB), 1024, 0, stream>>>(q, k, out);
}

// Round 6
// 63.290 us; speedup vs baseline: 2.0168x; 1.1466x over previous
//
#include <hip/hip_runtime.h>
#include <stdint.h>

// CandidateFinder: binary-quantize (x>0), exact match on two 32-bit dim
// groups (union), gather first <=64 matching key indices per query, pad -1.
//
// R5 -> R6: R5's fused kernel (~25us) paid 64x redundant key packing: every
// block re-read+re-packed its batch's full 512KB key slab (3.4us/CU L1 floor)
// with 64 SGPRs of live ballot results defeating load batching. R2-vs-R5
// showed an extra graph node costs ~nothing (70.2 vs 72.6). So: de-duplicated
// two-phase. Phase 1 packs each key row ONCE device-wide (8 rows/wave,
// branch-free). Phase 2: one wave per 2 queries, query sigs via 2 ballots,
// then 16 fully-branchless uint4 loads (2 keys/lane/load, sig table is
// 16KB/batch -> L1/L2-hot, loads batch: no exec toggles in unrolled body),
// scalar acc|=ballot / cnt+=popc. Ordered emit in wave-uniform rare path
// (p ~ 2^-26) = reference's sort-then-truncate exactly.

#define LSEQ 2048
#define DDIM 64
#define KMAX 64
#define RPW  8    // rows packed per wave in sig kernel

// Phase 1: pack key sign bits. wave=64 lanes <-> 64 dims, __ballot(v>0) IS
// the row's two 32-bit group signatures in canonical bit order.
__global__ __launch_bounds__(256) void sig_kernel(
    const float* __restrict__ key, uint2* __restrict__ ksig, int nrows) {
    int wid  = (int)((blockIdx.x * blockDim.x + threadIdx.x) >> 6);
    int lane = threadIdx.x & 63;
    int row0 = wid * RPW;
    if (row0 >= nrows) return;                      // wave-uniform
    const float* base = key + (size_t)row0 * DDIM + lane;
    float v[RPW];
#pragma unroll
    for (int u = 0; u < RPW; ++u)                   // 8 loads, one BB
        v[u] = base[(size_t)u * DDIM];              // 256B/wave coalesced
    unsigned long long m[RPW];
#pragma unroll
    for (int u = 0; u < RPW; ++u)
        m[u] = __ballot(v[u] > 0.0f);               // branchless, scalar dst
    if (lane == 0) {                                // one exec toggle
#pragma unroll
        for (int u = 0; u < RPW; ++u)               // 64B contiguous
            ksig[row0 + u] = make_uint2((unsigned)m[u], (unsigned)(m[u] >> 32));
    }
}

// Phase 2: one wave per 2 queries; scan batch's 2048 key sigs as 16
// branchless uint4 loads (lane holds keys 2*(i*64+lane), +1).
__global__ __launch_bounds__(256) void match_kernel(
    const float* __restrict__ query, const uint2* __restrict__ ksig,
    int* __restrict__ out, int nq) {
    int wid  = (int)((blockIdx.x * blockDim.x + threadIdx.x) >> 6);
    int lane = threadIdx.x & 63;
    int q0 = wid * 2;
    if (q0 >= nq) return;                           // wave-uniform
    int b = q0 >> 11;                               // q0 / LSEQ

    // query signatures via ballot (rows read once, coalesced)
    const float* qp = query + (size_t)q0 * DDIM + lane;
    float v0 = qp[0], v1 = qp[DDIM];
    unsigned long long qm0 = __ballot(v0 > 0.0f);
    unsigned long long qm1 = __ballot(v1 > 0.0f);
    unsigned a0 = (unsigned)qm0, g0 = (unsigned)(qm0 >> 32);
    unsigned a1 = (unsigned)qm1, g1 = (unsigned)(qm1 >> 32);

    // fast path: 16 uint4 loads, zero exec-mask toggles -> all in flight
    const uint4* kt = (const uint4*)(ksig + (size_t)b * LSEQ) + lane;
    unsigned long long acc0 = 0, acc1 = 0;
    int cnt0 = 0, cnt1 = 0;
#pragma unroll
    for (int i = 0; i < LSEQ / 128; ++i) {          // 16 iters, 128 keys each
        uint4 kv = kt[(size_t)i * 64];              // 1KB/wave, L1/L2-hot
        bool mA0 = (kv.x == a0) | (kv.y == g0);     // key 2*(i*64+lane)
        bool mB0 = (kv.z == a0) | (kv.w == g0);     // key 2*(i*64+lane)+1
        bool mA1 = (kv.x == a1) | (kv.y == g1);
        bool mB1 = (kv.z == a1) | (kv.w == g1);
        unsigned long long s;
        s = __ballot(mA0); acc0 |= s; cnt0 += __popcll(s);
        s = __ballot(mB0); acc0 |= s; cnt0 += __popcll(s);
        s = __ballot(mA1); acc1 |= s; cnt1 += __popcll(s);
        s = __ballot(mB1); acc1 |= s; cnt1 += __popcll(s);
    }

    int* o0 = out + (size_t)q0 * KMAX;
    int* o1 = o0 + KMAX;

    if (acc0 | acc1) {                              // wave-uniform, p~2^-26:
        // exact ordered emit (ascending key index = sort-then-truncate)
        const uint2* ks = ksig + (size_t)b * LSEQ;
        unsigned long long below = (1ull << lane) - 1ull;
        for (int t = 0; t < 2; ++t) {
            unsigned qa = t ? a1 : a0, qg = t ? g1 : g0;
            int* ob = t ? o1 : o0;
            int c2 = 0;
            for (int c = 0; c < LSEQ / 64; ++c) {
                uint2 kv = ks[c * 64 + lane];
                bool m = (kv.x == qa) || (kv.y == qg);
                unsigned long long mask = __ballot(m);
                if (m) {
                    int pos = c2 + __popcll(mask & below);
                    if (pos < KMAX) ob[pos] = c * 64 + lane;
                }
                c2 += __popcll(mask);
            }
        }
    }
    // pad with -1 (KMAX == 64 lanes; disjoint from emitted positions)
    if (lane >= cnt0) o0[lane] = -1;
    if (lane >= cnt1) o1[lane] = -1;
}

// Fallback (ws too small): R5's single fused kernel, known-correct.
#define QPB  32
#define NW   16
#define GROUP 32
__global__ __launch_bounds__(1024) void fused_kernel(
    const float* __restrict__ query, const float* __restrict__ key,
    int* __restrict__ out) {
    __shared__ uint2 ks[LSEQ];
    const int bpb  = LSEQ / QPB;
    int b    = blockIdx.x / bpb;
    int qblk = blockIdx.x % bpb;
    int lane = threadIdx.x & 63;
    int wave = threadIdx.x >> 6;
    const float* kb = key + (size_t)b * LSEQ * DDIM;
    for (int g = 0; g < LSEQ / NW / GROUP; ++g) {
        float v[GROUP];
#pragma unroll
        for (int u = 0; u < GROUP; ++u)
            v[u] = kb[(size_t)(g * (NW * GROUP) + u * NW + wave) * DDIM + lane];
        unsigned long long m[GROUP];
#pragma unroll
        for (int u = 0; u < GROUP; ++u) m[u] = __ballot(v[u] > 0.0f);
        if (lane == 0) {
#pragma unroll
            for (int u = 0; u < GROUP; ++u)
                ks[g * (NW * GROUP) + u * NW + wave] =
                    make_uint2((unsigned)m[u], (unsigned)(m[u] >> 32));
        }
    }
    const float* qb = query + ((size_t)b * LSEQ + (size_t)qblk * QPB) * DDIM;
    int q0 = wave * 2;
    float v0 = qb[(size_t)q0 * DDIM + lane];
    float v1 = qb[(size_t)(q0 + 1) * DDIM + lane];
    unsigned long long m0 = __ballot(v0 > 0.0f);
    unsigned long long m1 = __ballot(v1 > 0.0f);
    __syncthreads();
    unsigned long long below = (1ull << lane) - 1ull;
    for (int t = 0; t < 2; ++t) {
        unsigned long long qm = t ? m1 : m0;
        unsigned q1 = (unsigned)qm, q2 = (unsigned)(qm >> 32);
        int* obase = out + ((size_t)b * LSEQ + (size_t)qblk * QPB + q0 + t) * KMAX;
        unsigned long long acc = 0;
        int cnt = 0;
#pragma unroll
        for (int c = 0; c < LSEQ / 64; ++c) {
            uint2 kv = ks[c * 64 + lane];
            bool m = (kv.x == q1) || (kv.y == q2);
            unsigned long long mask = __ballot(m);
            acc |= mask; cnt += __popcll(mask);
        }
        if (acc != 0) {
            int c2 = 0;
            for (int c = 0; c < LSEQ / 64; ++c) {
                uint2 kv = ks[c * 64 + lane];
                bool m = (kv.x == q1) || (kv.y == q2);
                unsigned long long mask = __ballot(m);
                if (m) {
                    int pos = c2 + __popcll(mask & below);
                    if (pos < KMAX) obase[pos] = c * 64 + lane;
                }
                c2 += __popcll(mask);
            }
        }
        if (lane >= cnt) obase[lane] = -1;
    }
}

extern "C" void kernel_launch(void* const* d_in, const int* in_sizes, int n_in,
                              void* d_out, int out_size, void* d_ws, size_t ws_size,
                              hipStream_t stream) {
    const float* q = (const float*)d_in[0];
    const float* k = (const float*)d_in[1];
    // d_in[2] = head_idx, unused (inputs are already per-head)
    int* out = (int*)d_out;

    int total = in_sizes[0];             // B * L * D
    int B = total / (LSEQ * DDIM);       // = 4
    int nrows = B * LSEQ;                // 8192

    if (ws_size >= (size_t)nrows * sizeof(uint2)) {
        uint2* ksig = (uint2*)d_ws;
        int sig_waves = nrows / RPW;                 // 1024 waves
        sig_kernel<<<sig_waves * 64 / 256, 256, 0, stream>>>(k, ksig, nrows);
        int match_waves = nrows / 2;                 // 4096 waves
        match_kernel<<<match_waves * 64 / 256, 256, 0, stream>>>(q, ksig, out, nrows);
    } else {
        fused_kernel<<<B * (LSEQ / QPB), 1024, 0, stream>>>(q, k, out);
    }
}